// Round 2
// baseline (485.564 us; speedup 1.0000x reference)
//
#include <hip/hip_runtime.h>
#include <hip/hip_bf16.h>
#include <math.h>

#define N_NODES 50000
#define N_EDGES 1600000
#define IN_CH   128
#define OUT_CH  64
#define N_HEADS 4
#define CH      (N_HEADS * OUT_CH)   // 256
#define CAP     128                  // bucket capacity (in-degree ~Poisson(32), max ~60)

// ---------- helpers ----------
__device__ __forceinline__ float bf16_lo(unsigned u) { return __uint_as_float(u << 16); }
__device__ __forceinline__ float bf16_hi(unsigned u) { return __uint_as_float(u & 0xffff0000u); }
__device__ __forceinline__ unsigned short f_to_bf16(float f) {
  unsigned u = __float_as_uint(f);
  u += 0x7fffu + ((u >> 16) & 1u);   // RNE
  return (unsigned short)(u >> 16);
}

// ---------- kernel 1: x_msg = x @ W (W staged bf16 in LDS) + fused s,t terms ----------
// block = 256 (4 waves); wave = 8 nodes x 256 ch (4 ch/lane). 50000 % 8 == 0.
__global__ __launch_bounds__(256) void gemm_kernel(
    const float* __restrict__ x, const float* __restrict__ w,
    const float* __restrict__ aw,
    unsigned short* __restrict__ xmsg,       // bf16 bits [N_NODES][256]
    float* __restrict__ sbuf, float* __restrict__ tbuf)
{
  __shared__ __align__(16) unsigned short wlds[IN_CH][CH];   // 65536 B

  // stage W (fp32 -> bf16) once per block
  for (int i = threadIdx.x; i < N_HEADS * IN_CH * OUT_CH; i += 256) {
    int h = i >> 13, k = (i >> 6) & (IN_CH - 1), o = i & (OUT_CH - 1);
    wlds[k][(h << 6) | o] = f_to_bf16(w[i]);
  }
  __syncthreads();

  const int lane = threadIdx.x & 63;
  const int wave = __builtin_amdgcn_readfirstlane(threadIdx.x >> 6);
  const int m0 = (blockIdx.x * 4 + wave) * 8;
  if (m0 >= N_NODES) return;

  const int c = lane * 4;          // channels c..c+3
  const int h = c >> 6;
  const int o = c & 63;

  float acc[8][4];
  #pragma unroll
  for (int mi = 0; mi < 8; ++mi) { acc[mi][0]=0.f; acc[mi][1]=0.f; acc[mi][2]=0.f; acc[mi][3]=0.f; }

  for (int k = 0; k < IN_CH; k += 4) {
    ushort4 wv0 = *(const ushort4*)&wlds[k+0][c];
    ushort4 wv1 = *(const ushort4*)&wlds[k+1][c];
    ushort4 wv2 = *(const ushort4*)&wlds[k+2][c];
    ushort4 wv3 = *(const ushort4*)&wlds[k+3][c];
    float f00=bf16_lo(wv0.x), f01=bf16_lo(wv0.y), f02=bf16_lo(wv0.z), f03=bf16_lo(wv0.w);
    float f10=bf16_lo(wv1.x), f11=bf16_lo(wv1.y), f12=bf16_lo(wv1.z), f13=bf16_lo(wv1.w);
    float f20=bf16_lo(wv2.x), f21=bf16_lo(wv2.y), f22=bf16_lo(wv2.z), f23=bf16_lo(wv2.w);
    float f30=bf16_lo(wv3.x), f31=bf16_lo(wv3.y), f32=bf16_lo(wv3.z), f33=bf16_lo(wv3.w);
    #pragma unroll
    for (int mi = 0; mi < 8; ++mi) {
      float4 xv = *(const float4*)(x + (size_t)(m0 + mi) * IN_CH + k);
      acc[mi][0] = fmaf(xv.x, f00, acc[mi][0]);
      acc[mi][1] = fmaf(xv.x, f01, acc[mi][1]);
      acc[mi][2] = fmaf(xv.x, f02, acc[mi][2]);
      acc[mi][3] = fmaf(xv.x, f03, acc[mi][3]);
      acc[mi][0] = fmaf(xv.y, f10, acc[mi][0]);
      acc[mi][1] = fmaf(xv.y, f11, acc[mi][1]);
      acc[mi][2] = fmaf(xv.y, f12, acc[mi][2]);
      acc[mi][3] = fmaf(xv.y, f13, acc[mi][3]);
      acc[mi][0] = fmaf(xv.z, f20, acc[mi][0]);
      acc[mi][1] = fmaf(xv.z, f21, acc[mi][1]);
      acc[mi][2] = fmaf(xv.z, f22, acc[mi][2]);
      acc[mi][3] = fmaf(xv.z, f23, acc[mi][3]);
      acc[mi][0] = fmaf(xv.w, f30, acc[mi][0]);
      acc[mi][1] = fmaf(xv.w, f31, acc[mi][1]);
      acc[mi][2] = fmaf(xv.w, f32, acc[mi][2]);
      acc[mi][3] = fmaf(xv.w, f33, acc[mi][3]);
    }
  }

  float4 aws = *(const float4*)(aw + h * (2*OUT_CH) + o);
  float4 awt = *(const float4*)(aw + h * (2*OUT_CH) + OUT_CH + o);

  #pragma unroll
  for (int mi = 0; mi < 8; ++mi) {
    ushort4 pk;
    pk.x = f_to_bf16(acc[mi][0]);
    pk.y = f_to_bf16(acc[mi][1]);
    pk.z = f_to_bf16(acc[mi][2]);
    pk.w = f_to_bf16(acc[mi][3]);
    *(ushort4*)(xmsg + (size_t)(m0 + mi) * CH + c) = pk;

    float sv = acc[mi][0]*aws.x + acc[mi][1]*aws.y + acc[mi][2]*aws.z + acc[mi][3]*aws.w;
    float tv = acc[mi][0]*awt.x + acc[mi][1]*awt.y + acc[mi][2]*awt.z + acc[mi][3]*awt.w;
    #pragma unroll
    for (int off = 8; off; off >>= 1) {
      sv += __shfl_xor(sv, off);
      tv += __shfl_xor(tv, off);
    }
    if ((lane & 15) == 0) {
      sbuf[(m0 + mi) * 4 + h] = sv;
      tbuf[(m0 + mi) * 4 + h] = tv;
    }
  }
}

// ---------- kernel 2: bucket-CSR build by target node ----------
__global__ __launch_bounds__(256) void build_buckets(
    const int* __restrict__ etgt, int* __restrict__ deg, int* __restrict__ bucket)
{
  int e = blockIdx.x * 256 + threadIdx.x;
  if (e >= N_EDGES) return;
  int t = etgt[e];
  int pos = atomicAdd(&deg[t], 1);
  if (pos < CAP) bucket[t * CAP + pos] = e;
}

// ---------- kernel 3: per-node online-softmax + pipelined gather-aggregate ----------
// one wave per node; scores computed ONCE, p cached in LDS; 4-deep load pipeline
__global__ __launch_bounds__(256) void aggregate_kernel(
    const int* __restrict__ deg, const int* __restrict__ bucket,
    const int* __restrict__ esrc, const float* __restrict__ eval,
    const float* __restrict__ sbuf, const float* __restrict__ tbuf,
    const unsigned short* __restrict__ xmsg, float* __restrict__ out)
{
  const int lane = threadIdx.x & 63;
  const int wave = threadIdx.x >> 6;
  const int n = blockIdx.x * 4 + wave;
  if (n >= N_NODES) return;

  __shared__ __align__(16) float p_lds[4][64][4];
  __shared__ int s_lds[4][64];

  const int d = min(deg[n], CAP);
  const int h4 = lane >> 4;                      // head owning this lane's 4 channels

  float4 tn4 = *(const float4*)(tbuf + (size_t)n * 4);
  float tn[4] = {tn4.x, tn4.y, tn4.z, tn4.w};

  float m[4]    = {-INFINITY, -INFINITY, -INFINITY, -INFINITY};
  float psum[4] = {0.f, 0.f, 0.f, 0.f};
  float acc[4]  = {0.f, 0.f, 0.f, 0.f};

  for (int base = 0; base < d; base += 64) {     // runs once for d<=64 (typical)
    const int cnt = min(64, d - base);
    const bool act = lane < cnt;

    // score for this lane's edge (all 4 heads), computed exactly once
    float sc[4] = {-INFINITY, -INFINITY, -INFINITY, -INFINITY};
    int s = 0;
    if (act) {
      int e = bucket[n * CAP + base + lane];
      s = esrc[e];
      float v = eval[e];
      float4 sv4 = *(const float4*)(sbuf + (size_t)s * 4);
      float svv[4] = {sv4.x, sv4.y, sv4.z, sv4.w};
      #pragma unroll
      for (int hh = 0; hh < 4; ++hh) {
        float t = svv[hh] + tn[hh];
        t = (t > 0.f) ? t : 0.01f * t;           // leaky_relu
        sc[hh] = t * v;
      }
    }

    // batch max per head, wave-wide
    float bm[4] = {sc[0], sc[1], sc[2], sc[3]};
    #pragma unroll
    for (int hh = 0; hh < 4; ++hh)
      #pragma unroll
      for (int off = 32; off; off >>= 1)
        bm[hh] = fmaxf(bm[hh], __shfl_xor(bm[hh], off));

    // online-softmax rescale
    float p[4];
    #pragma unroll
    for (int hh = 0; hh < 4; ++hh) {
      float nm = fmaxf(m[hh], bm[hh]);
      float r = (m[hh] == -INFINITY) ? 0.f : __expf(m[hh] - nm);
      psum[hh] *= r;
      if (hh == h4) { acc[0]*=r; acc[1]*=r; acc[2]*=r; acc[3]*=r; }
      m[hh] = nm;
      p[hh] = act ? __expf(sc[hh] - nm) : 0.f;
      psum[hh] += p[hh];
    }

    if (act) {
      s_lds[wave][lane] = s;
      *(float4*)(&p_lds[wave][lane][0]) = make_float4(p[0], p[1], p[2], p[3]);
    }
    __builtin_amdgcn_wave_barrier();

    // pipelined gather-FMA: 4 loads in flight
    int k = 0;
    for (; k + 4 <= cnt; k += 4) {
      int s0 = s_lds[wave][k+0];
      int s1 = s_lds[wave][k+1];
      int s2 = s_lds[wave][k+2];
      int s3 = s_lds[wave][k+3];
      uint2 r0 = *((const uint2*)(xmsg + (size_t)s0 * CH) + lane);
      uint2 r1 = *((const uint2*)(xmsg + (size_t)s1 * CH) + lane);
      uint2 r2 = *((const uint2*)(xmsg + (size_t)s2 * CH) + lane);
      uint2 r3 = *((const uint2*)(xmsg + (size_t)s3 * CH) + lane);
      float q0 = p_lds[wave][k+0][h4];
      float q1 = p_lds[wave][k+1][h4];
      float q2 = p_lds[wave][k+2][h4];
      float q3 = p_lds[wave][k+3][h4];
      acc[0] = fmaf(q0, bf16_lo(r0.x), acc[0]);
      acc[1] = fmaf(q0, bf16_hi(r0.x), acc[1]);
      acc[2] = fmaf(q0, bf16_lo(r0.y), acc[2]);
      acc[3] = fmaf(q0, bf16_hi(r0.y), acc[3]);
      acc[0] = fmaf(q1, bf16_lo(r1.x), acc[0]);
      acc[1] = fmaf(q1, bf16_hi(r1.x), acc[1]);
      acc[2] = fmaf(q1, bf16_lo(r1.y), acc[2]);
      acc[3] = fmaf(q1, bf16_hi(r1.y), acc[3]);
      acc[0] = fmaf(q2, bf16_lo(r2.x), acc[0]);
      acc[1] = fmaf(q2, bf16_hi(r2.x), acc[1]);
      acc[2] = fmaf(q2, bf16_lo(r2.y), acc[2]);
      acc[3] = fmaf(q2, bf16_hi(r2.y), acc[3]);
      acc[0] = fmaf(q3, bf16_lo(r3.x), acc[0]);
      acc[1] = fmaf(q3, bf16_hi(r3.x), acc[1]);
      acc[2] = fmaf(q3, bf16_lo(r3.y), acc[2]);
      acc[3] = fmaf(q3, bf16_hi(r3.y), acc[3]);
    }
    for (; k < cnt; ++k) {
      int s0 = s_lds[wave][k];
      uint2 r0 = *((const uint2*)(xmsg + (size_t)s0 * CH) + lane);
      float q0 = p_lds[wave][k][h4];
      acc[0] = fmaf(q0, bf16_lo(r0.x), acc[0]);
      acc[1] = fmaf(q0, bf16_hi(r0.x), acc[1]);
      acc[2] = fmaf(q0, bf16_lo(r0.y), acc[2]);
      acc[3] = fmaf(q0, bf16_hi(r0.y), acc[3]);
    }
    __builtin_amdgcn_wave_barrier();
  }

  #pragma unroll
  for (int hh = 0; hh < 4; ++hh)
    #pragma unroll
    for (int off = 32; off; off >>= 1)
      psum[hh] += __shfl_xor(psum[hh], off);
  float rs = psum[h4];
  float inv = (rs > 0.f) ? 1.0f / rs : 0.f;
  float4 o4 = make_float4(acc[0]*inv, acc[1]*inv, acc[2]*inv, acc[3]*inv);
  *(float4*)(out + (size_t)n * CH + lane * 4) = o4;
}

// ---------- launch ----------
extern "C" void kernel_launch(void* const* d_in, const int* in_sizes, int n_in,
                              void* d_out, int out_size, void* d_ws, size_t ws_size,
                              hipStream_t stream) {
  const float* x    = (const float*)d_in[0];
  const int*   etgt = (const int*)  d_in[1];
  const int*   esrc = (const int*)  d_in[2];
  const float* evl  = (const float*)d_in[3];
  const float* w    = (const float*)d_in[4];
  const float* aw   = (const float*)d_in[5];
  float* out = (float*)d_out;

  char* ws = (char*)d_ws;
  unsigned short* xmsg = (unsigned short*)(ws);              // 25,600,000 B
  float* sbuf  = (float*)(ws + 25600000);                    //    800,000 B
  float* tbuf  = (float*)(ws + 26400000);                    //    800,000 B
  int*   deg   = (int*)  (ws + 27200000);                    //    200,000 B
  int*   bucket= (int*)  (ws + 27400000);                    // 25,600,000 B

  hipMemsetAsync(deg, 0, N_NODES * sizeof(int), stream);

  gemm_kernel<<<(N_NODES + 31) / 32, 256, 0, stream>>>(x, w, aw, xmsg, sbuf, tbuf);
  build_buckets<<<(N_EDGES + 255) / 256, 256, 0, stream>>>(etgt, deg, bucket);
  aggregate_kernel<<<(N_NODES + 3) / 4, 256, 0, stream>>>(deg, bucket, esrc, evl,
                                                          sbuf, tbuf, xmsg, out);
}

// Round 3
// 348.551 us; speedup vs baseline: 1.3931x; 1.3931x over previous
//
#include <hip/hip_runtime.h>
#include <hip/hip_bf16.h>
#include <math.h>

#define N_NODES 50000
#define N_EDGES 1600000
#define IN_CH   128
#define OUT_CH  64
#define N_HEADS 4
#define CH      (N_HEADS * OUT_CH)   // 256
#define CAP     128                  // bucket capacity (max in-degree of Poisson(32) over 50k ~ 58)

typedef __attribute__((ext_vector_type(8))) short bf16x8;
typedef __attribute__((ext_vector_type(4))) float f32x4;

// ---------- helpers ----------
__device__ __forceinline__ float bf16_lo(unsigned u) { return __uint_as_float(u << 16); }
__device__ __forceinline__ float bf16_hi(unsigned u) { return __uint_as_float(u & 0xffff0000u); }
__device__ __forceinline__ unsigned short f_to_bf16(float f) {
  unsigned u = __float_as_uint(f);
  u += 0x7fffu + ((u >> 16) & 1u);   // RNE
  return (unsigned short)(u >> 16);
}

// ---------- kernel 0: swizzle W (fp32 [4][128][64]) into bf16 B-fragment order ----------
// layout: wb[((kc*16 + ctg)*64 + lane)*8 + j] = bf16(W[k= kc*32+(lane>>4)*8+j][n= ctg*16+(lane&15)])
__global__ __launch_bounds__(256) void convert_w(
    const float* __restrict__ w, unsigned short* __restrict__ wb)
{
  int i = blockIdx.x * 256 + threadIdx.x;          // 32768 total
  if (i >= N_HEADS * IN_CH * OUT_CH) return;
  int j = i & 7, lane = (i >> 3) & 63, ctg = (i >> 9) & 15, kc = i >> 13;
  int k = kc * 32 + (lane >> 4) * 8 + j;
  int n = ctg * 16 + (lane & 15);
  int h = n >> 6, o = n & 63;
  wb[i] = f_to_bf16(w[(h * IN_CH + k) * OUT_CH + o]);
}

// ---------- kernel 1: MFMA GEMM x(50000x128) @ W(128x256) -> xmsg bf16 (+ fused s,t) ----------
// block 256 = 4 waves. wave = 32 rows (2 MFMA slabs) x 128 cols (8 ct). waves 0/1 = col halves
// of rows blk*64..+31; waves 2/3 = rows +32..+63. No LDS.
__global__ __launch_bounds__(256) void gemm_mfma(
    const float* __restrict__ x, const unsigned short* __restrict__ wb,
    const float* __restrict__ aw,
    unsigned short* __restrict__ xmsg, float* __restrict__ sbuf, float* __restrict__ tbuf)
{
  const int lane = threadIdx.x & 63;
  const int wv   = threadIdx.x >> 6;
  const int q    = lane >> 4;
  const int l16  = lane & 15;
  const int rowbase = blockIdx.x * 64 + (wv >> 1) * 32;
  const int chalf   = wv & 1;

  // A-frags: A[m=lane&15][k=q*8+j], fp32 loads -> bf16
  bf16x8 afrag[2][4];
  #pragma unroll
  for (int s = 0; s < 2; ++s) {
    int r = rowbase + s * 16 + l16;
    r = min(r, N_NODES - 1);
    const float* xp = x + (size_t)r * IN_CH + q * 8;
    #pragma unroll
    for (int kc = 0; kc < 4; ++kc) {
      f32x4 lo = *(const f32x4*)(xp + kc * 32);
      f32x4 hi = *(const f32x4*)(xp + kc * 32 + 4);
      bf16x8 a;
      a[0] = (short)f_to_bf16(lo[0]); a[1] = (short)f_to_bf16(lo[1]);
      a[2] = (short)f_to_bf16(lo[2]); a[3] = (short)f_to_bf16(lo[3]);
      a[4] = (short)f_to_bf16(hi[0]); a[5] = (short)f_to_bf16(hi[1]);
      a[6] = (short)f_to_bf16(hi[2]); a[7] = (short)f_to_bf16(hi[3]);
      afrag[s][kc] = a;
    }
  }

  f32x4 acc[2][8];
  #pragma unroll
  for (int s = 0; s < 2; ++s)
    #pragma unroll
    for (int ct = 0; ct < 8; ++ct)
      acc[s][ct] = (f32x4){0.f, 0.f, 0.f, 0.f};

  #pragma unroll
  for (int kc = 0; kc < 4; ++kc) {
    #pragma unroll
    for (int ct = 0; ct < 8; ++ct) {
      const int ctg = chalf * 8 + ct;
      bf16x8 b = *(const bf16x8*)(wb + ((size_t)(kc * 16 + ctg) * 64 + lane) * 8);
      acc[0][ct] = __builtin_amdgcn_mfma_f32_16x16x32_bf16(afrag[0][kc], b, acc[0][ct], 0, 0, 0);
      acc[1][ct] = __builtin_amdgcn_mfma_f32_16x16x32_bf16(afrag[1][kc], b, acc[1][ct], 0, 0, 0);
    }
  }

  // epilogue: C/D layout col=lane&15, row=q*4+reg
  #pragma unroll
  for (int s = 0; s < 2; ++s) {
    float ps[2][4] = {{0,0,0,0},{0,0,0,0}};
    float pt[2][4] = {{0,0,0,0},{0,0,0,0}};
    #pragma unroll
    for (int ct = 0; ct < 8; ++ct) {
      int col = chalf * 128 + ct * 16 + l16;
      int h = col >> 6;
      float as_ = aw[h * 128 + (col & 63)];
      float at_ = aw[h * 128 + 64 + (col & 63)];
      int hp = ct >> 2;
      #pragma unroll
      for (int reg = 0; reg < 4; ++reg) {
        float v = acc[s][ct][reg];
        ps[hp][reg] += v * as_;
        pt[hp][reg] += v * at_;
      }
    }
    #pragma unroll
    for (int hp = 0; hp < 2; ++hp)
      #pragma unroll
      for (int reg = 0; reg < 4; ++reg)
        #pragma unroll
        for (int off = 1; off < 16; off <<= 1) {
          ps[hp][reg] += __shfl_xor(ps[hp][reg], off);
          pt[hp][reg] += __shfl_xor(pt[hp][reg], off);
        }

    const int rowq = rowbase + s * 16 + q * 4;
    if (l16 == 0) {
      #pragma unroll
      for (int reg = 0; reg < 4; ++reg) {
        int r = rowq + reg;
        if (r < N_NODES) {
          #pragma unroll
          for (int hp = 0; hp < 2; ++hp) {
            sbuf[r * 4 + chalf * 2 + hp] = ps[hp][reg];
            tbuf[r * 4 + chalf * 2 + hp] = pt[hp][reg];
          }
        }
      }
    }
    #pragma unroll
    for (int reg = 0; reg < 4; ++reg) {
      int r = rowq + reg;
      if (r < N_NODES) {
        #pragma unroll
        for (int ct = 0; ct < 8; ++ct)
          xmsg[(size_t)r * CH + chalf * 128 + ct * 16 + l16] = f_to_bf16(acc[s][ct][reg]);
      }
    }
  }
}

// ---------- kernel 2: bucket-CSR build; bucket entry = {src, eval bits} ----------
__global__ __launch_bounds__(256) void build_buckets(
    const int* __restrict__ etgt, const int* __restrict__ esrc,
    const float* __restrict__ eval, int* __restrict__ deg, int2* __restrict__ bucket)
{
  int e = blockIdx.x * 256 + threadIdx.x;
  if (e >= N_EDGES) return;
  int t = etgt[e];
  int pos = atomicAdd(&deg[t], 1);
  if (pos < CAP) bucket[(size_t)t * CAP + pos] = make_int2(esrc[e], __float_as_int(eval[e]));
}

// ---------- kernel 3: per-node online-softmax + 16B/lane paired gather ----------
// wave per node. score phase: 1 edge/lane. gather phase: lane = 16B segment (8 ch),
// halves process edge pairs, 4 pairs (8 edges) in flight.
__global__ __launch_bounds__(256) void aggregate_kernel(
    const int* __restrict__ deg, const int2* __restrict__ bucket,
    const float* __restrict__ sbuf, const float* __restrict__ tbuf,
    const unsigned short* __restrict__ xmsg, float* __restrict__ out)
{
  const int lane = threadIdx.x & 63;
  const int wave = threadIdx.x >> 6;
  const int n = blockIdx.x * 4 + wave;
  if (n >= N_NODES) return;

  __shared__ __align__(16) float p_lds[4][64][4];
  __shared__ int s_lds[4][64];

  const int d = min(deg[n], CAP);
  const int seg  = lane & 31;
  const int half = lane >> 5;
  const int hh4  = seg >> 3;          // head of this lane's 8 channels

  float4 tn4 = *(const float4*)(tbuf + (size_t)n * 4);
  float tn[4] = {tn4.x, tn4.y, tn4.z, tn4.w};

  float m[4]    = {-INFINITY, -INFINITY, -INFINITY, -INFINITY};
  float psum[4] = {0.f, 0.f, 0.f, 0.f};
  float acc[8]  = {0.f, 0.f, 0.f, 0.f, 0.f, 0.f, 0.f, 0.f};

  for (int base = 0; base < d; base += 64) {
    const int cnt = min(64, d - base);
    const bool act = lane < cnt;

    float sc[4] = {-INFINITY, -INFINITY, -INFINITY, -INFINITY};
    int s = 0;
    if (act) {
      int2 ev = bucket[(size_t)n * CAP + base + lane];
      s = ev.x;
      float v = __int_as_float(ev.y);
      float4 sv4 = *(const float4*)(sbuf + (size_t)s * 4);
      float svv[4] = {sv4.x, sv4.y, sv4.z, sv4.w};
      #pragma unroll
      for (int hh = 0; hh < 4; ++hh) {
        float t = svv[hh] + tn[hh];
        t = (t > 0.f) ? t : 0.01f * t;           // leaky_relu
        sc[hh] = t * v;
      }
    }

    float bm[4] = {sc[0], sc[1], sc[2], sc[3]};
    #pragma unroll
    for (int hh = 0; hh < 4; ++hh)
      #pragma unroll
      for (int off = 32; off; off >>= 1)
        bm[hh] = fmaxf(bm[hh], __shfl_xor(bm[hh], off));

    float p[4];
    #pragma unroll
    for (int hh = 0; hh < 4; ++hh) {
      float nm = fmaxf(m[hh], bm[hh]);
      float r = (m[hh] == -INFINITY) ? 0.f : __expf(m[hh] - nm);
      psum[hh] *= r;
      if (hh == hh4) {
        #pragma unroll
        for (int j = 0; j < 8; ++j) acc[j] *= r;
      }
      m[hh] = nm;
      p[hh] = act ? __expf(sc[hh] - nm) : 0.f;
      psum[hh] += p[hh];
    }

    if (act) {
      s_lds[wave][lane] = s;
      *(float4*)(&p_lds[wave][lane][0]) = make_float4(p[0], p[1], p[2], p[3]);
    }
    __builtin_amdgcn_wave_barrier();

    int k = 0;
    for (; k + 8 <= cnt; k += 8) {
      int sA = s_lds[wave][k + 0 + half];
      int sB = s_lds[wave][k + 2 + half];
      int sC = s_lds[wave][k + 4 + half];
      int sD = s_lds[wave][k + 6 + half];
      uint4 rA = *(const uint4*)(xmsg + (size_t)sA * CH + seg * 8);
      uint4 rB = *(const uint4*)(xmsg + (size_t)sB * CH + seg * 8);
      uint4 rC = *(const uint4*)(xmsg + (size_t)sC * CH + seg * 8);
      uint4 rD = *(const uint4*)(xmsg + (size_t)sD * CH + seg * 8);
      float qA = p_lds[wave][k + 0 + half][hh4];
      float qB = p_lds[wave][k + 2 + half][hh4];
      float qC = p_lds[wave][k + 4 + half][hh4];
      float qD = p_lds[wave][k + 6 + half][hh4];
      acc[0] = fmaf(qA, bf16_lo(rA.x), acc[0]); acc[1] = fmaf(qA, bf16_hi(rA.x), acc[1]);
      acc[2] = fmaf(qA, bf16_lo(rA.y), acc[2]); acc[3] = fmaf(qA, bf16_hi(rA.y), acc[3]);
      acc[4] = fmaf(qA, bf16_lo(rA.z), acc[4]); acc[5] = fmaf(qA, bf16_hi(rA.z), acc[5]);
      acc[6] = fmaf(qA, bf16_lo(rA.w), acc[6]); acc[7] = fmaf(qA, bf16_hi(rA.w), acc[7]);
      acc[0] = fmaf(qB, bf16_lo(rB.x), acc[0]); acc[1] = fmaf(qB, bf16_hi(rB.x), acc[1]);
      acc[2] = fmaf(qB, bf16_lo(rB.y), acc[2]); acc[3] = fmaf(qB, bf16_hi(rB.y), acc[3]);
      acc[4] = fmaf(qB, bf16_lo(rB.z), acc[4]); acc[5] = fmaf(qB, bf16_hi(rB.z), acc[5]);
      acc[6] = fmaf(qB, bf16_lo(rB.w), acc[6]); acc[7] = fmaf(qB, bf16_hi(rB.w), acc[7]);
      acc[0] = fmaf(qC, bf16_lo(rC.x), acc[0]); acc[1] = fmaf(qC, bf16_hi(rC.x), acc[1]);
      acc[2] = fmaf(qC, bf16_lo(rC.y), acc[2]); acc[3] = fmaf(qC, bf16_hi(rC.y), acc[3]);
      acc[4] = fmaf(qC, bf16_lo(rC.z), acc[4]); acc[5] = fmaf(qC, bf16_hi(rC.z), acc[5]);
      acc[6] = fmaf(qC, bf16_lo(rC.w), acc[6]); acc[7] = fmaf(qC, bf16_hi(rC.w), acc[7]);
      acc[0] = fmaf(qD, bf16_lo(rD.x), acc[0]); acc[1] = fmaf(qD, bf16_hi(rD.x), acc[1]);
      acc[2] = fmaf(qD, bf16_lo(rD.y), acc[2]); acc[3] = fmaf(qD, bf16_hi(rD.y), acc[3]);
      acc[4] = fmaf(qD, bf16_lo(rD.z), acc[4]); acc[5] = fmaf(qD, bf16_hi(rD.z), acc[5]);
      acc[6] = fmaf(qD, bf16_lo(rD.w), acc[6]); acc[7] = fmaf(qD, bf16_hi(rD.w), acc[7]);
    }
    for (; k < cnt; k += 2) {
      int e = k + half;
      if (e < cnt) {
        int sA = s_lds[wave][e];
        uint4 rA = *(const uint4*)(xmsg + (size_t)sA * CH + seg * 8);
        float qA = p_lds[wave][e][hh4];
        acc[0] = fmaf(qA, bf16_lo(rA.x), acc[0]); acc[1] = fmaf(qA, bf16_hi(rA.x), acc[1]);
        acc[2] = fmaf(qA, bf16_lo(rA.y), acc[2]); acc[3] = fmaf(qA, bf16_hi(rA.y), acc[3]);
        acc[4] = fmaf(qA, bf16_lo(rA.z), acc[4]); acc[5] = fmaf(qA, bf16_hi(rA.z), acc[5]);
        acc[6] = fmaf(qA, bf16_lo(rA.w), acc[6]); acc[7] = fmaf(qA, bf16_hi(rA.w), acc[7]);
      }
    }
    __builtin_amdgcn_wave_barrier();
  }

  #pragma unroll
  for (int j = 0; j < 8; ++j) acc[j] += __shfl_xor(acc[j], 32);
  #pragma unroll
  for (int hh = 0; hh < 4; ++hh)
    #pragma unroll
    for (int off = 32; off; off >>= 1)
      psum[hh] += __shfl_xor(psum[hh], off);

  float rs = psum[hh4];
  float inv = (rs > 0.f) ? 1.0f / rs : 0.f;
  const int o = half * 4;
  float4 o4 = make_float4(acc[o+0]*inv, acc[o+1]*inv, acc[o+2]*inv, acc[o+3]*inv);
  *(float4*)(out + (size_t)n * CH + seg * 8 + half * 4) = o4;
}

// ---------- launch ----------
extern "C" void kernel_launch(void* const* d_in, const int* in_sizes, int n_in,
                              void* d_out, int out_size, void* d_ws, size_t ws_size,
                              hipStream_t stream) {
  const float* x    = (const float*)d_in[0];
  const int*   etgt = (const int*)  d_in[1];
  const int*   esrc = (const int*)  d_in[2];
  const float* evl  = (const float*)d_in[3];
  const float* w    = (const float*)d_in[4];
  const float* aw   = (const float*)d_in[5];
  float* out = (float*)d_out;

  char* ws = (char*)d_ws;
  unsigned short* wb   = (unsigned short*)(ws);              //     65,536 B
  unsigned short* xmsg = (unsigned short*)(ws + 65536);      // 25,600,000 B
  float* sbuf   = (float*)(ws + 25665536);                   //    800,000 B
  float* tbuf   = (float*)(ws + 26465536);                   //    800,000 B
  int*   deg    = (int*)  (ws + 27265536);                   //    200,000 B
  int2*  bucket = (int2*) (ws + 27465536);                   // 51,200,000 B
  // total: 78,665,536 B

  hipMemsetAsync(deg, 0, N_NODES * sizeof(int), stream);

  convert_w<<<128, 256, 0, stream>>>(w, wb);
  gemm_mfma<<<(N_NODES + 63) / 64, 256, 0, stream>>>(x, wb, aw, xmsg, sbuf, tbuf);
  build_buckets<<<(N_EDGES + 255) / 256, 256, 0, stream>>>(etgt, esrc, evl, deg, bucket);
  aggregate_kernel<<<(N_NODES + 3) / 4, 256, 0, stream>>>(deg, bucket, sbuf, tbuf, xmsg, out);
}

// Round 4
// 288.519 us; speedup vs baseline: 1.6830x; 1.2081x over previous
//
#include <hip/hip_runtime.h>
#include <hip/hip_bf16.h>
#include <math.h>

#define N_NODES 50000
#define N_EDGES 1600000
#define IN_CH   128
#define OUT_CH  64
#define N_HEADS 4
#define CH      (N_HEADS * OUT_CH)   // 256

#define NPB   64                     // nodes per bin
#define BINS  782                    // ceil(50000/64)
#define CAPB  3072                   // per-bin edge capacity (avg 2048, sigma~45)
#define CHUNK 8000                   // edges per bin_scatter block (200*8000 = 1.6M)

typedef __attribute__((ext_vector_type(8))) short bf16x8;
typedef __attribute__((ext_vector_type(4))) float f32x4;

// ---------- helpers ----------
__device__ __forceinline__ float bf16_lo(unsigned u) { return __uint_as_float(u << 16); }
__device__ __forceinline__ float bf16_hi(unsigned u) { return __uint_as_float(u & 0xffff0000u); }
__device__ __forceinline__ unsigned short f_to_bf16(float f) {
  unsigned u = __float_as_uint(f);
  u += 0x7fffu + ((u >> 16) & 1u);   // RNE
  return (unsigned short)(u >> 16);
}

// ---------- kernel 0: swizzle W (fp32 [4][128][64]) into bf16 B-fragment order ----------
__global__ __launch_bounds__(256) void convert_w(
    const float* __restrict__ w, unsigned short* __restrict__ wb)
{
  int i = blockIdx.x * 256 + threadIdx.x;          // 32768 total
  if (i >= N_HEADS * IN_CH * OUT_CH) return;
  int j = i & 7, lane = (i >> 3) & 63, ctg = (i >> 9) & 15, kc = i >> 13;
  int k = kc * 32 + (lane >> 4) * 8 + j;
  int n = ctg * 16 + (lane & 15);
  int h = n >> 6, o = n & 63;
  wb[i] = f_to_bf16(w[(h * IN_CH + k) * OUT_CH + o]);
}

// ---------- kernel 0b: init per-bin cursors ----------
__global__ __launch_bounds__(256) void init_cursors(int* __restrict__ gcur)
{
  int b = blockIdx.x * 256 + threadIdx.x;
  if (b < BINS) gcur[b] = b * CAPB;
}

// ---------- kernel 1: MFMA GEMM + LDS-transposed coalesced epilogue ----------
// block 256 = 4 waves. wave = 32 rows x 128 cols. waves 0/1 = col halves of rows
// blk*64..+31; waves 2/3 = rows +32..+63.
__global__ __launch_bounds__(256) void gemm_mfma(
    const float* __restrict__ x, const unsigned short* __restrict__ wb,
    const float* __restrict__ aw,
    unsigned short* __restrict__ xmsg, float* __restrict__ sbuf, float* __restrict__ tbuf)
{
  __shared__ __align__(16) unsigned short tlds[4][32][128];   // 32 KB

  const int lane = threadIdx.x & 63;
  const int wv   = threadIdx.x >> 6;
  const int q    = lane >> 4;
  const int l16  = lane & 15;
  const int rowbase = blockIdx.x * 64 + (wv >> 1) * 32;
  const int chalf   = wv & 1;

  // A-frags: A[m=lane&15][k=q*8+j], fp32 loads -> bf16
  bf16x8 afrag[2][4];
  #pragma unroll
  for (int s = 0; s < 2; ++s) {
    int r = rowbase + s * 16 + l16;
    r = min(r, N_NODES - 1);
    const float* xp = x + (size_t)r * IN_CH + q * 8;
    #pragma unroll
    for (int kc = 0; kc < 4; ++kc) {
      f32x4 lo = *(const f32x4*)(xp + kc * 32);
      f32x4 hi = *(const f32x4*)(xp + kc * 32 + 4);
      bf16x8 a;
      a[0] = (short)f_to_bf16(lo[0]); a[1] = (short)f_to_bf16(lo[1]);
      a[2] = (short)f_to_bf16(lo[2]); a[3] = (short)f_to_bf16(lo[3]);
      a[4] = (short)f_to_bf16(hi[0]); a[5] = (short)f_to_bf16(hi[1]);
      a[6] = (short)f_to_bf16(hi[2]); a[7] = (short)f_to_bf16(hi[3]);
      afrag[s][kc] = a;
    }
  }

  f32x4 acc[2][8];
  #pragma unroll
  for (int s = 0; s < 2; ++s)
    #pragma unroll
    for (int ct = 0; ct < 8; ++ct)
      acc[s][ct] = (f32x4){0.f, 0.f, 0.f, 0.f};

  #pragma unroll
  for (int kc = 0; kc < 4; ++kc) {
    #pragma unroll
    for (int ct = 0; ct < 8; ++ct) {
      const int ctg = chalf * 8 + ct;
      bf16x8 b = *(const bf16x8*)(wb + ((size_t)(kc * 16 + ctg) * 64 + lane) * 8);
      acc[0][ct] = __builtin_amdgcn_mfma_f32_16x16x32_bf16(afrag[0][kc], b, acc[0][ct], 0, 0, 0);
      acc[1][ct] = __builtin_amdgcn_mfma_f32_16x16x32_bf16(afrag[1][kc], b, acc[1][ct], 0, 0, 0);
    }
  }

  // stage C-tile (bf16) into LDS; C/D layout: col=l16, row=q*4+reg
  #pragma unroll
  for (int s = 0; s < 2; ++s)
    #pragma unroll
    for (int ct = 0; ct < 8; ++ct)
      #pragma unroll
      for (int reg = 0; reg < 4; ++reg)
        tlds[wv][s * 16 + q * 4 + reg][ct * 16 + l16] = f_to_bf16(acc[s][ct][reg]);

  // fused s,t terms (register path, unchanged)
  #pragma unroll
  for (int s = 0; s < 2; ++s) {
    float ps[2][4] = {{0,0,0,0},{0,0,0,0}};
    float pt[2][4] = {{0,0,0,0},{0,0,0,0}};
    #pragma unroll
    for (int ct = 0; ct < 8; ++ct) {
      int col = chalf * 128 + ct * 16 + l16;
      int h = col >> 6;
      float as_ = aw[h * 128 + (col & 63)];
      float at_ = aw[h * 128 + 64 + (col & 63)];
      int hp = ct >> 2;
      #pragma unroll
      for (int reg = 0; reg < 4; ++reg) {
        float v = acc[s][ct][reg];
        ps[hp][reg] += v * as_;
        pt[hp][reg] += v * at_;
      }
    }
    #pragma unroll
    for (int hp = 0; hp < 2; ++hp)
      #pragma unroll
      for (int reg = 0; reg < 4; ++reg)
        #pragma unroll
        for (int off = 1; off < 16; off <<= 1) {
          ps[hp][reg] += __shfl_xor(ps[hp][reg], off);
          pt[hp][reg] += __shfl_xor(pt[hp][reg], off);
        }
    const int rowq = rowbase + s * 16 + q * 4;
    if (l16 == 0) {
      #pragma unroll
      for (int reg = 0; reg < 4; ++reg) {
        int r = rowq + reg;
        if (r < N_NODES) {
          #pragma unroll
          for (int hp = 0; hp < 2; ++hp) {
            sbuf[r * 4 + chalf * 2 + hp] = ps[hp][reg];
            tbuf[r * 4 + chalf * 2 + hp] = pt[hp][reg];
          }
        }
      }
    }
  }

  __syncthreads();

  // coalesced xmsg store: 2 rows / instruction, 256B contiguous per half-wave
  const int seg  = lane & 31;
  const int half = lane >> 5;
  #pragma unroll
  for (int r2 = 0; r2 < 16; ++r2) {
    int row = r2 * 2 + half;
    int gr = rowbase + row;
    if (gr < N_NODES) {
      ushort4 vv = *(const ushort4*)&tlds[wv][row][seg * 4];
      *(ushort4*)(xmsg + (size_t)gr * CH + chalf * 128 + seg * 4) = vv;
    }
  }
}

// ---------- kernel 2a: binned ranked scatter ----------
// entry: {src | tgt_local<<16, eval_bits}
__global__ __launch_bounds__(256) void bin_scatter(
    const int* __restrict__ etgt, const int* __restrict__ esrc,
    const float* __restrict__ eval, int* __restrict__ gcur, int2* __restrict__ binned)
{
  __shared__ int lhist[BINS];
  __shared__ int lbase[BINS];
  __shared__ unsigned short stg[CHUNK];   // tgt fits in 16 bits (50000 < 65536)

  const int tid = threadIdx.x;
  const int e0 = blockIdx.x * CHUNK;
  const int n = min(CHUNK, N_EDGES - e0);

  for (int b = tid; b < BINS; b += 256) lhist[b] = 0;
  __syncthreads();

  for (int i = tid; i < n; i += 256) {
    int t = etgt[e0 + i];
    stg[i] = (unsigned short)t;
    atomicAdd(&lhist[t >> 6], 1);
  }
  __syncthreads();

  for (int b = tid; b < BINS; b += 256) {
    int c = lhist[b];
    lbase[b] = c ? atomicAdd(&gcur[b], c) : 0;
    lhist[b] = 0;                        // reuse as rank counter
  }
  __syncthreads();

  for (int i = tid; i < n; i += 256) {
    int t = (int)stg[i];
    int b = t >> 6;
    int r = atomicAdd(&lhist[b], 1);
    int pos = lbase[b] + r;
    if (pos < (b + 1) * CAPB) {          // overflow guard
      int pack = esrc[e0 + i] | ((t & 63) << 16);
      binned[pos] = make_int2(pack, __float_as_int(eval[e0 + i]));
    }
  }
}

// ---------- kernel 2b: per-bin LDS counting sort -> per-node CSR ----------
__global__ __launch_bounds__(256) void build_csr(
    const int* __restrict__ gcur, const int2* __restrict__ binned,
    int2* __restrict__ csr, int* __restrict__ deg, int* __restrict__ rowstart)
{
  __shared__ int nh[NPB];
  __shared__ int npre[NPB];
  __shared__ __align__(16) int2 stg[CAPB];    // 24 KB

  const int tid = threadIdx.x;
  const int b = blockIdx.x;
  const int base = b * CAPB;
  const int cnt = min(gcur[b] - base, CAPB);

  if (tid < NPB) nh[tid] = 0;
  __syncthreads();

  for (int i = tid; i < cnt; i += 256) {
    int2 e = binned[base + i];
    stg[i] = e;
    atomicAdd(&nh[(e.x >> 16) & 63], 1);
  }
  __syncthreads();

  if (tid < 64) {                       // wave 0: exclusive prefix over 64 counters
    int v = nh[tid];
    int sc = v;
    #pragma unroll
    for (int off = 1; off < 64; off <<= 1) {
      int u = __shfl_up(sc, off);
      if (tid >= off) sc += u;
    }
    npre[tid] = sc - v;
    int node = b * NPB + tid;
    if (node < N_NODES) { deg[node] = v; rowstart[node] = base + sc - v; }
    nh[tid] = 0;                        // reuse as rank counter
  }
  __syncthreads();

  for (int i = tid; i < cnt; i += 256) {
    int2 e = stg[i];
    int tl = (e.x >> 16) & 63;
    int r = atomicAdd(&nh[tl], 1);
    csr[base + npre[tl] + r] = e;
  }
}

// ---------- kernel 3: per-node online-softmax + 16B/lane paired gather ----------
__global__ __launch_bounds__(256) void aggregate_kernel(
    const int* __restrict__ deg, const int* __restrict__ rowstart,
    const int2* __restrict__ csr,
    const float* __restrict__ sbuf, const float* __restrict__ tbuf,
    const unsigned short* __restrict__ xmsg, float* __restrict__ out)
{
  const int lane = threadIdx.x & 63;
  const int wave = threadIdx.x >> 6;
  const int n = blockIdx.x * 4 + wave;
  if (n >= N_NODES) return;

  __shared__ __align__(16) float p_lds[4][64][4];
  __shared__ int s_lds[4][64];

  const int d = deg[n];
  const int rs0 = rowstart[n];
  const int seg  = lane & 31;
  const int half = lane >> 5;
  const int hh4  = seg >> 3;          // head of this lane's 8 channels

  float4 tn4 = *(const float4*)(tbuf + (size_t)n * 4);
  float tn[4] = {tn4.x, tn4.y, tn4.z, tn4.w};

  float m[4]    = {-INFINITY, -INFINITY, -INFINITY, -INFINITY};
  float psum[4] = {0.f, 0.f, 0.f, 0.f};
  float acc[8]  = {0.f, 0.f, 0.f, 0.f, 0.f, 0.f, 0.f, 0.f};

  for (int base = 0; base < d; base += 64) {
    const int cnt = min(64, d - base);
    const bool act = lane < cnt;

    float sc[4] = {-INFINITY, -INFINITY, -INFINITY, -INFINITY};
    int s = 0;
    if (act) {
      int2 ev = csr[(size_t)rs0 + base + lane];
      s = ev.x & 0xffff;
      float v = __int_as_float(ev.y);
      float4 sv4 = *(const float4*)(sbuf + (size_t)s * 4);
      float svv[4] = {sv4.x, sv4.y, sv4.z, sv4.w};
      #pragma unroll
      for (int hh = 0; hh < 4; ++hh) {
        float t = svv[hh] + tn[hh];
        t = (t > 0.f) ? t : 0.01f * t;           // leaky_relu
        sc[hh] = t * v;
      }
    }

    float bm[4] = {sc[0], sc[1], sc[2], sc[3]};
    #pragma unroll
    for (int hh = 0; hh < 4; ++hh)
      #pragma unroll
      for (int off = 32; off; off >>= 1)
        bm[hh] = fmaxf(bm[hh], __shfl_xor(bm[hh], off));

    float p[4];
    #pragma unroll
    for (int hh = 0; hh < 4; ++hh) {
      float nm = fmaxf(m[hh], bm[hh]);
      float r = (m[hh] == -INFINITY) ? 0.f : __expf(m[hh] - nm);
      psum[hh] *= r;
      if (hh == hh4) {
        #pragma unroll
        for (int j = 0; j < 8; ++j) acc[j] *= r;
      }
      m[hh] = nm;
      p[hh] = act ? __expf(sc[hh] - nm) : 0.f;
      psum[hh] += p[hh];
    }

    if (act) {
      s_lds[wave][lane] = s;
      *(float4*)(&p_lds[wave][lane][0]) = make_float4(p[0], p[1], p[2], p[3]);
    }
    __builtin_amdgcn_wave_barrier();

    int k = 0;
    for (; k + 8 <= cnt; k += 8) {
      int sA = s_lds[wave][k + 0 + half];
      int sB = s_lds[wave][k + 2 + half];
      int sC = s_lds[wave][k + 4 + half];
      int sD = s_lds[wave][k + 6 + half];
      uint4 rA = *(const uint4*)(xmsg + (size_t)sA * CH + seg * 8);
      uint4 rB = *(const uint4*)(xmsg + (size_t)sB * CH + seg * 8);
      uint4 rC = *(const uint4*)(xmsg + (size_t)sC * CH + seg * 8);
      uint4 rD = *(const uint4*)(xmsg + (size_t)sD * CH + seg * 8);
      float qA = p_lds[wave][k + 0 + half][hh4];
      float qB = p_lds[wave][k + 2 + half][hh4];
      float qC = p_lds[wave][k + 4 + half][hh4];
      float qD = p_lds[wave][k + 6 + half][hh4];
      acc[0] = fmaf(qA, bf16_lo(rA.x), acc[0]); acc[1] = fmaf(qA, bf16_hi(rA.x), acc[1]);
      acc[2] = fmaf(qA, bf16_lo(rA.y), acc[2]); acc[3] = fmaf(qA, bf16_hi(rA.y), acc[3]);
      acc[4] = fmaf(qA, bf16_lo(rA.z), acc[4]); acc[5] = fmaf(qA, bf16_hi(rA.z), acc[5]);
      acc[6] = fmaf(qA, bf16_lo(rA.w), acc[6]); acc[7] = fmaf(qA, bf16_hi(rA.w), acc[7]);
      acc[0] = fmaf(qB, bf16_lo(rB.x), acc[0]); acc[1] = fmaf(qB, bf16_hi(rB.x), acc[1]);
      acc[2] = fmaf(qB, bf16_lo(rB.y), acc[2]); acc[3] = fmaf(qB, bf16_hi(rB.y), acc[3]);
      acc[4] = fmaf(qB, bf16_lo(rB.z), acc[4]); acc[5] = fmaf(qB, bf16_hi(rB.z), acc[5]);
      acc[6] = fmaf(qB, bf16_lo(rB.w), acc[6]); acc[7] = fmaf(qB, bf16_hi(rB.w), acc[7]);
      acc[0] = fmaf(qC, bf16_lo(rC.x), acc[0]); acc[1] = fmaf(qC, bf16_hi(rC.x), acc[1]);
      acc[2] = fmaf(qC, bf16_lo(rC.y), acc[2]); acc[3] = fmaf(qC, bf16_hi(rC.y), acc[3]);
      acc[4] = fmaf(qC, bf16_lo(rC.z), acc[4]); acc[5] = fmaf(qC, bf16_hi(rC.z), acc[5]);
      acc[6] = fmaf(qC, bf16_lo(rC.w), acc[6]); acc[7] = fmaf(qC, bf16_hi(rC.w), acc[7]);
      acc[0] = fmaf(qD, bf16_lo(rD.x), acc[0]); acc[1] = fmaf(qD, bf16_hi(rD.x), acc[1]);
      acc[2] = fmaf(qD, bf16_lo(rD.y), acc[2]); acc[3] = fmaf(qD, bf16_hi(rD.y), acc[3]);
      acc[4] = fmaf(qD, bf16_lo(rD.z), acc[4]); acc[5] = fmaf(qD, bf16_hi(rD.z), acc[5]);
      acc[6] = fmaf(qD, bf16_lo(rD.w), acc[6]); acc[7] = fmaf(qD, bf16_hi(rD.w), acc[7]);
    }
    for (; k < cnt; k += 2) {
      int e = k + half;
      if (e < cnt) {
        int sA = s_lds[wave][e];
        uint4 rA = *(const uint4*)(xmsg + (size_t)sA * CH + seg * 8);
        float qA = p_lds[wave][e][hh4];
        acc[0] = fmaf(qA, bf16_lo(rA.x), acc[0]); acc[1] = fmaf(qA, bf16_hi(rA.x), acc[1]);
        acc[2] = fmaf(qA, bf16_lo(rA.y), acc[2]); acc[3] = fmaf(qA, bf16_hi(rA.y), acc[3]);
        acc[4] = fmaf(qA, bf16_lo(rA.z), acc[4]); acc[5] = fmaf(qA, bf16_hi(rA.z), acc[5]);
        acc[6] = fmaf(qA, bf16_lo(rA.w), acc[6]); acc[7] = fmaf(qA, bf16_hi(rA.w), acc[7]);
      }
    }
    __builtin_amdgcn_wave_barrier();
  }

  #pragma unroll
  for (int j = 0; j < 8; ++j) acc[j] += __shfl_xor(acc[j], 32);
  #pragma unroll
  for (int hh = 0; hh < 4; ++hh)
    #pragma unroll
    for (int off = 32; off; off >>= 1)
      psum[hh] += __shfl_xor(psum[hh], off);

  float rs = psum[hh4];
  float inv = (rs > 0.f) ? 1.0f / rs : 0.f;
  const int o = half * 4;
  float4 o4 = make_float4(acc[o+0]*inv, acc[o+1]*inv, acc[o+2]*inv, acc[o+3]*inv);
  *(float4*)(out + (size_t)n * CH + seg * 8 + half * 4) = o4;
}

// ---------- launch ----------
extern "C" void kernel_launch(void* const* d_in, const int* in_sizes, int n_in,
                              void* d_out, int out_size, void* d_ws, size_t ws_size,
                              hipStream_t stream) {
  const float* x    = (const float*)d_in[0];
  const int*   etgt = (const int*)  d_in[1];
  const int*   esrc = (const int*)  d_in[2];
  const float* evl  = (const float*)d_in[3];
  const float* w    = (const float*)d_in[4];
  const float* aw   = (const float*)d_in[5];
  float* out = (float*)d_out;

  char* ws = (char*)d_ws;
  unsigned short* wb   = (unsigned short*)(ws);              //      65,536 B
  unsigned short* xmsg = (unsigned short*)(ws + 65536);      //  25,600,000 B
  float* sbuf     = (float*)(ws + 25665536);                 //     800,000 B
  float* tbuf     = (float*)(ws + 26465536);                 //     800,000 B
  int*   gcur     = (int*)  (ws + 27265536);                 //       4,096 B
  int*   deg      = (int*)  (ws + 27269632);                 //     200,704 B
  int*   rowstart = (int*)  (ws + 27470336);                 //     200,704 B
  int2*  binned   = (int2*) (ws + 27671040);                 //  19,218,432 B
  int2*  csr      = (int2*) (ws + 46889472);                 //  19,218,432 B
  // total: 66,107,904 B

  init_cursors<<<4, 256, 0, stream>>>(gcur);
  convert_w<<<128, 256, 0, stream>>>(w, wb);
  gemm_mfma<<<(N_NODES + 63) / 64, 256, 0, stream>>>(x, wb, aw, xmsg, sbuf, tbuf);
  bin_scatter<<<(N_EDGES + CHUNK - 1) / CHUNK, 256, 0, stream>>>(etgt, esrc, evl, gcur, binned);
  build_csr<<<BINS, 256, 0, stream>>>(gcur, binned, csr, deg, rowstart);
  aggregate_kernel<<<(N_NODES + 3) / 4, 256, 0, stream>>>(deg, rowstart, csr,
                                                          sbuf, tbuf, xmsg, out);
}